// Round 12
// baseline (177.212 us; speedup 1.0000x reference)
//
#include <hip/hip_runtime.h>

typedef _Float16 h2 __attribute__((ext_vector_type(2)));
typedef _Float16 h8 __attribute__((ext_vector_type(8)));
typedef float f4 __attribute__((ext_vector_type(4)));

#define BB 256
#define II 1152
#define QQ 8
#define JJ 10
#define PP 16

#define BT 16            // b per block (R0/R9 proven)
#define IT 8             // i per block
#define NBT (BB / BT)    // 16
#define NIT (II / IT)    // 144
#define XRH 72           // halfs per staged-x b-row (64 + 8 pad)
#define WTILE (IT * PP * QQ)     // 1024 halfs per j in the LDS W-tile

#define NW (JJ * II * PP * QQ)   // 1474560
#define NX (BB * II * QQ)        // 2359296
#define NS (BB * JJ * PP)        // 40960
#define LOG2E 1.4426950408889634f

// ---------------------------------------------------------------------------
// 16-lane row sum via DPP — f32 (for vv_kernel) and packed-f16 (hot loop).
// ---------------------------------------------------------------------------
template <int CTRL>
__device__ __forceinline__ float dpp_add(float v) {
    int s = __builtin_bit_cast(int, v);
    int t = __builtin_amdgcn_update_dpp(0, s, CTRL, 0xF, 0xF, true);
    return v + __builtin_bit_cast(float, t);
}
__device__ __forceinline__ float row_sum16(float v) {
    v = dpp_add<0xB1>(v);   // xor1
    v = dpp_add<0x4E>(v);   // xor2
    v = dpp_add<0x124>(v);  // row_ror:4
    v = dpp_add<0x128>(v);  // row_ror:8
    return v;
}
template <int CTRL>
__device__ __forceinline__ h2 dpp_add_pk(h2 v) {
    int s = __builtin_bit_cast(int, v);
    int t = __builtin_amdgcn_update_dpp(0, s, CTRL, 0xF, 0xF, true);
    return v + __builtin_bit_cast(h2, t);   // v_pk_add_f16
}
__device__ __forceinline__ h2 row_sum16_pk(h2 v) {
    v = dpp_add_pk<0xB1>(v);
    v = dpp_add_pk<0x4E>(v);
    v = dpp_add_pk<0x124>(v);
    v = dpp_add_pk<0x128>(v);
    return v;
}

// 8-element f16 dot with fp32 accumulate: 4 x v_dot2_f32_f16.
__device__ __forceinline__ float dot8(h8 w, h8 x) {
    h2 w0 = __builtin_shufflevector(w, w, 0, 1), w1 = __builtin_shufflevector(w, w, 2, 3);
    h2 w2 = __builtin_shufflevector(w, w, 4, 5), w3 = __builtin_shufflevector(w, w, 6, 7);
    h2 x0 = __builtin_shufflevector(x, x, 0, 1), x1 = __builtin_shufflevector(x, x, 2, 3);
    h2 x2 = __builtin_shufflevector(x, x, 4, 5), x3 = __builtin_shufflevector(x, x, 6, 7);
    float acc = __builtin_amdgcn_fdot2(w0, x0, 0.0f, false);
    acc = __builtin_amdgcn_fdot2(w1, x1, acc, false);
    acc = __builtin_amdgcn_fdot2(w2, x2, acc, false);
    acc = __builtin_amdgcn_fdot2(w3, x3, acc, false);
    return acc;
}

// ---------------------------------------------------------------------------
// prep: W,X fp32 -> f16 (natural Xh + transposed XT[i][b][q] for s0);
// zero S0/S1/S2.
// ---------------------------------------------------------------------------
__global__ __launch_bounds__(256) void prep_kernel(
    const float* __restrict__ X, const float* __restrict__ W,
    _Float16* __restrict__ Xh, _Float16* __restrict__ Wh,
    _Float16* __restrict__ XT,
    float* __restrict__ S)   // 3*NS floats
{
    const int g = blockIdx.x * 256 + threadIdx.x;
    const int stride = gridDim.x * 256;
    typedef _Float16 h4 __attribute__((ext_vector_type(4)));
    for (int k = g; k < NW / 4; k += stride) {
        const float4 f = ((const float4*)W)[k];
        h4 o = { (_Float16)f.x, (_Float16)f.y, (_Float16)f.z, (_Float16)f.w };
        ((h4*)Wh)[k] = o;
    }
    for (int k = g; k < NX / 4; k += stride) {
        const float4 f = ((const float4*)X)[k];
        h4 o = { (_Float16)f.x, (_Float16)f.y, (_Float16)f.z, (_Float16)f.w };
        ((h4*)Xh)[k] = o;
        // transposed copy XT[(i*256 + b)*8 + q]
        const int e0 = k * 4;
        const int b  = e0 / (II * QQ);
        const int r  = e0 - b * (II * QQ);
        const int i  = r >> 3;
        const int q  = r & 7;
        *(h4*)(XT + ((size_t)i * BB + b) * QQ + q) = o;
    }
    const float4 z = {0.f, 0.f, 0.f, 0.f};
    for (int k = g; k < 3 * NS / 4; k += stride) ((float4*)S)[k] = z;
}

// ---------------------------------------------------------------------------
// s0 via MFMA: s0 = 0.1 * GEMM over K=(i,q)=9216; coalesced A via XT.
// ---------------------------------------------------------------------------
__global__ __launch_bounds__(256) void s0_mfma_kernel(
    const _Float16* __restrict__ XT, const _Float16* __restrict__ Wh,
    float* __restrict__ S0)
{
    const int wid  = blockIdx.x * 4 + (threadIdx.x >> 6);  // 0..1279
    const int lane = threadIdx.x & 63;
    const int bt  = wid / 80;
    const int rem = wid % 80;
    const int j   = rem >> 3;
    const int kc  = rem & 7;
    const int b0  = bt * 16;
    const int m    = lane & 15;
    const int quad = lane >> 4;
    const int ib   = kc * 144;

    const _Float16* ax = XT + ((size_t)(ib + quad) * BB + b0 + m) * QQ;
    const _Float16* bw = Wh + (((size_t)j * II + ib + quad) * PP + m) * QQ;

    f4 acc = {0.f, 0.f, 0.f, 0.f};
    for (int t = 0; t < 36; ++t) {
        const h8 a = *(const h8*)ax;
        const h8 b = *(const h8*)bw;
        acc = __builtin_amdgcn_mfma_f32_16x16x32_f16(a, b, acc, 0, 0, 0);
        ax += (size_t)4 * BB * QQ;
        bw += (size_t)4 * PP * QQ;
    }
#pragma unroll
    for (int r = 0; r < 4; ++r)
        atomicAdd(&S0[((size_t)(b0 + quad * 4 + r) * JJ + j) * PP + m], 0.1f * acc[r]);
}

// ---------------------------------------------------------------------------
// vv_kernel: squash + logit-weight precompute.
//  MODE 0: v = squash(S);  V0raw = v;  VV = v * log2e      (after s0)
//  MODE 1: v = squash(S);  VV = (v + V0raw) * log2e        (after pass 1)
// ---------------------------------------------------------------------------
template <int MODE>
__global__ __launch_bounds__(256) void vv_kernel(
    const float* __restrict__ S, float* __restrict__ V0raw,
    float* __restrict__ VV)
{
    const int idx = blockIdx.x * 256 + threadIdx.x;   // 0..NS-1
    const float s = S[idx];
    const float n2 = row_sum16(s * s);
    const float sc = n2 * __builtin_amdgcn_rcpf(1.0f + n2)
                        * __builtin_amdgcn_rsqf(n2 + 1e-7f);
    const float v = s * sc;
    if (MODE == 0) {
        V0raw[idx] = v;
        VV[idx] = v * LOG2E;
    } else {
        VV[idx] = (v + V0raw[idx]) * LOG2E;
    }
}

// ---------------------------------------------------------------------------
// Fused routing pass — R9 structure (131.6 us best) with ONE change:
// software-pipelined LDS reads.  The i+1 W fragments + x are issued into
// registers BEFORE softmax(i) executes, hiding the ~120cy DS latency under
// ~250cy of softmax VALU (R10/R11 ledger: the stall is the serial
// ds_read->dot8->DPP->exp2 chain, not DS bandwidth or VALU issue).
// ---------------------------------------------------------------------------
__global__ __launch_bounds__(256, 4) void pass_kernel(
    const _Float16* __restrict__ Xh,  // [B][I][Q] f16
    const _Float16* __restrict__ Wh,  // [J][I][P][Q] f16
    const float* __restrict__ VV,     // [B][J][P] = v * log2e
    float* __restrict__ Sout)         // [B][J][P] pre-zeroed accumulator
{
    __shared__ _Float16 ws[JJ * WTILE];  // 20 KB
    __shared__ _Float16 xs[BT * XRH];    // 2.25 KB

    // XCD-bijective swizzle (grid 2304 = 8 XCD * 288)
    const int L  = blockIdx.x;
    const int xc = L & 7;
    const int k8 = L >> 3;               // 0..287
    const int bt = 2 * xc + (k8 & 1);
    const int it = k8 >> 1;              // 0..143
    const int b0 = bt * BT;
    const int i0 = it * IT;
    const int tid = threadIdx.x;

    // ---- stage W tile: 1280 h8 chunks, 5 per thread (coalesced 16B/lane)
    {
        const size_t jstride = (size_t)II * PP * QQ;
        const _Float16* wsrc = Wh + (size_t)i0 * PP * QQ;
#pragma unroll
        for (int k = 0; k < 5; ++k) {
            const int c = tid + k * 256;   // 0..1279
            const int j = c >> 7;          // 128 h8 chunks per j
            const int r = c & 127;
            *(h8*)(ws + j * WTILE + r * 8) = *(const h8*)(wsrc + j * jstride + r * 8);
        }
        if (tid < 128) {
            const int xb = tid >> 3;
            const int xr = tid & 7;
            *(h8*)(xs + xb * XRH + xr * 8) =
                *(const h8*)(Xh + ((size_t)(b0 + xb) * II + i0) * QQ + xr * 8);
        }
    }
    __syncthreads();

    const int b_l = tid >> 4;
    const int p   = tid & 15;
    const int b   = b0 + b_l;

    // precomputed vv, packed once into 5 h2 (j-pairs)
    h2 vvpk[5];
#pragma unroll
    for (int jp = 0; jp < JJ; jp += 2) {
        const float v0 = VV[((size_t)b * JJ + jp) * PP + p];
        const float v1 = VV[((size_t)b * JJ + jp + 1) * PP + p];
        vvpk[jp >> 1] = __builtin_bit_cast(h2, __builtin_amdgcn_cvt_pkrtz(v0, v1));
    }

    float sacc[JJ];
#pragma unroll
    for (int j = 0; j < JJ; ++j) sacc[j] = 0.0f;

    const _Float16* wb = ws + p * QQ;    // single LDS base; imm offsets below
    const _Float16* xb = xs + b_l * XRH;

    // ---- pipelined hot loop: reads for i+1 issued before softmax(i) ----
    h8 wf[JJ];
    h8 x8;
#pragma unroll
    for (int j = 0; j < JJ; ++j)
        wf[j] = *(const h8*)(wb + j * WTILE + 0 * PP * QQ);
    x8 = *(const h8*)(xb + 0 * QQ);

#pragma unroll
    for (int i = 0; i < IT; ++i) {
        // issue next-iteration LDS reads first (dead-code-eliminated at i=7)
        h8 wfn[JJ];
        h8 x8n;
        if (i + 1 < IT) {
#pragma unroll
            for (int j = 0; j < JJ; ++j)
                wfn[j] = *(const h8*)(wb + j * WTILE + (i + 1) * PP * QQ);
            x8n = *(const h8*)(xb + (i + 1) * QQ);
        }

        float h[JJ];
#pragma unroll
        for (int j = 0; j < JJ; ++j)
            h[j] = dot8(wf[j], x8);

        // packed-f16 16-lane logit reduction, j-pairs; product via pk_mul
        float e[JJ];
#pragma unroll
        for (int jp = 0; jp < JJ; jp += 2) {
            const h2 hp = __builtin_bit_cast(h2,
                __builtin_amdgcn_cvt_pkrtz(h[jp], h[jp + 1]));
            const h2 r = row_sum16_pk(vvpk[jp >> 1] * hp);
            e[jp]     = __builtin_amdgcn_exp2f((float)r.x);
            e[jp + 1] = __builtin_amdgcn_exp2f((float)r.y);
        }
        float a0 = (e[0] + e[1]) + (e[2] + e[3]);
        float a1 = (e[4] + e[5]) + (e[6] + e[7]);
        const float sum = (a0 + a1) + (e[8] + e[9]);
        const float inv = __builtin_amdgcn_rcpf(sum);
#pragma unroll
        for (int j = 0; j < JJ; ++j) sacc[j] += (e[j] * inv) * h[j];

        if (i + 1 < IT) {
#pragma unroll
            for (int j = 0; j < JJ; ++j) wf[j] = wfn[j];
            x8 = x8n;
        }
    }

#pragma unroll
    for (int j = 0; j < JJ; ++j)
        atomicAdd(&Sout[((size_t)b * JJ + j) * PP + p], sacc[j]);
}

// ---------------------------------------------------------------------------
// final output squash (fp32 precise)
// ---------------------------------------------------------------------------
__global__ __launch_bounds__(256) void squash_out_kernel(const float* __restrict__ S,
                                                         float* __restrict__ V)
{
    const int idx = blockIdx.x * blockDim.x + threadIdx.x;  // (b*J + j)
    if (idx >= BB * JJ) return;
    const float4* sp = (const float4*)(S + idx * PP);
    float4 a = sp[0], b4 = sp[1], c4 = sp[2], d4 = sp[3];
    float s2 = a.x * a.x + a.y * a.y + a.z * a.z + a.w * a.w +
               b4.x * b4.x + b4.y * b4.y + b4.z * b4.z + b4.w * b4.w +
               c4.x * c4.x + c4.y * c4.y + c4.z * c4.z + c4.w * c4.w +
               d4.x * d4.x + d4.y * d4.y + d4.z * d4.z + d4.w * d4.w;
    const float scale = s2 / (1.0f + s2) / sqrtf(s2 + 1e-7f);
    a.x *= scale; a.y *= scale; a.z *= scale; a.w *= scale;
    b4.x *= scale; b4.y *= scale; b4.z *= scale; b4.w *= scale;
    c4.x *= scale; c4.y *= scale; c4.z *= scale; c4.w *= scale;
    d4.x *= scale; d4.y *= scale; d4.z *= scale; d4.w *= scale;
    float4* vp = (float4*)(V + idx * PP);
    vp[0] = a; vp[1] = b4; vp[2] = c4; vp[3] = d4;
}

extern "C" void kernel_launch(void* const* d_in, const int* in_sizes, int n_in,
                              void* d_out, int out_size, void* d_ws, size_t ws_size,
                              hipStream_t stream)
{
    const float* X = (const float*)d_in[0];  // [256][1152][8]
    const float* W = (const float*)d_in[1];  // [10][1152][16][8]
    float* out = (float*)d_out;              // [256][10][16]

    _Float16* Xh = (_Float16*)d_ws;          // NX halfs
    _Float16* Wh = Xh + NX;                  // NW halfs
    _Float16* XT = Wh + NW;                  // NX halfs (transposed X for s0)
    float* S0 = (float*)(XT + NX);           // NS floats
    float* S1 = S0 + NS;
    float* S2 = S1 + NS;
    float* V0raw = S2 + NS;                  // NS floats
    float* VV1   = V0raw + NS;               // NS floats
    float* VV2   = VV1 + NS;                 // NS floats; total ~13.3 MB

    const int grid  = NBT * NIT;             // 2304 blocks of 256 threads
    const int vgrid = NS / 256;              // 160 blocks

    prep_kernel<<<1024, 256, 0, stream>>>(X, W, Xh, Wh, XT, S0);
    s0_mfma_kernel<<<320, 256, 0, stream>>>(XT, Wh, S0);
    vv_kernel<0><<<vgrid, 256, 0, stream>>>(S0, V0raw, VV1);
    pass_kernel<<<grid, 256, 0, stream>>>(Xh, Wh, VV1, S1);
    vv_kernel<1><<<vgrid, 256, 0, stream>>>(S1, V0raw, VV2);
    pass_kernel<<<grid, 256, 0, stream>>>(Xh, Wh, VV2, S2);
    squash_out_kernel<<<10, 256, 0, stream>>>(S2, out);
}

// Round 13
// 140.946 us; speedup vs baseline: 1.2573x; 1.2573x over previous
//
#include <hip/hip_runtime.h>

typedef _Float16 h2 __attribute__((ext_vector_type(2)));
typedef _Float16 h8 __attribute__((ext_vector_type(8)));
typedef float f4 __attribute__((ext_vector_type(4)));

#define BB 256
#define II 1152
#define QQ 8
#define JJ 10
#define PP 16

#define BT 32            // b per block (R13: 512-thread block, W shared by 32 b)
#define NTH 512          // threads per block
#define IT 8             // i per block
#define NBT (BB / BT)    // 8  (== 8 XCDs)
#define NIT (II / IT)    // 144
#define XRH 72           // halfs per staged-x b-row (64 + 8 pad)
#define WTILE (IT * PP * QQ)     // 1024 halfs per j in the LDS W-tile

#define NW (JJ * II * PP * QQ)   // 1474560
#define NX (BB * II * QQ)        // 2359296
#define NS (BB * JJ * PP)        // 40960
#define LOG2E 1.4426950408889634f

// ---------------------------------------------------------------------------
// 16-lane row sum via DPP — f32 (for vv_kernel) and packed-f16 (hot loop).
// ---------------------------------------------------------------------------
template <int CTRL>
__device__ __forceinline__ float dpp_add(float v) {
    int s = __builtin_bit_cast(int, v);
    int t = __builtin_amdgcn_update_dpp(0, s, CTRL, 0xF, 0xF, true);
    return v + __builtin_bit_cast(float, t);
}
__device__ __forceinline__ float row_sum16(float v) {
    v = dpp_add<0xB1>(v);   // xor1
    v = dpp_add<0x4E>(v);   // xor2
    v = dpp_add<0x124>(v);  // row_ror:4
    v = dpp_add<0x128>(v);  // row_ror:8
    return v;
}
template <int CTRL>
__device__ __forceinline__ h2 dpp_add_pk(h2 v) {
    int s = __builtin_bit_cast(int, v);
    int t = __builtin_amdgcn_update_dpp(0, s, CTRL, 0xF, 0xF, true);
    return v + __builtin_bit_cast(h2, t);   // v_pk_add_f16
}
__device__ __forceinline__ h2 row_sum16_pk(h2 v) {
    v = dpp_add_pk<0xB1>(v);
    v = dpp_add_pk<0x4E>(v);
    v = dpp_add_pk<0x124>(v);
    v = dpp_add_pk<0x128>(v);
    return v;
}

// 8-element f16 dot with fp32 accumulate: 4 x v_dot2_f32_f16.
__device__ __forceinline__ float dot8(h8 w, h8 x) {
    h2 w0 = __builtin_shufflevector(w, w, 0, 1), w1 = __builtin_shufflevector(w, w, 2, 3);
    h2 w2 = __builtin_shufflevector(w, w, 4, 5), w3 = __builtin_shufflevector(w, w, 6, 7);
    h2 x0 = __builtin_shufflevector(x, x, 0, 1), x1 = __builtin_shufflevector(x, x, 2, 3);
    h2 x2 = __builtin_shufflevector(x, x, 4, 5), x3 = __builtin_shufflevector(x, x, 6, 7);
    float acc = __builtin_amdgcn_fdot2(w0, x0, 0.0f, false);
    acc = __builtin_amdgcn_fdot2(w1, x1, acc, false);
    acc = __builtin_amdgcn_fdot2(w2, x2, acc, false);
    acc = __builtin_amdgcn_fdot2(w3, x3, acc, false);
    return acc;
}

// ---------------------------------------------------------------------------
// prep: W,X fp32 -> f16 (natural Xh + transposed XT[i][b][q] for s0);
// zero S0/S1/S2.
// ---------------------------------------------------------------------------
__global__ __launch_bounds__(256) void prep_kernel(
    const float* __restrict__ X, const float* __restrict__ W,
    _Float16* __restrict__ Xh, _Float16* __restrict__ Wh,
    _Float16* __restrict__ XT,
    float* __restrict__ S)   // 3*NS floats
{
    const int g = blockIdx.x * 256 + threadIdx.x;
    const int stride = gridDim.x * 256;
    typedef _Float16 h4 __attribute__((ext_vector_type(4)));
    for (int k = g; k < NW / 4; k += stride) {
        const float4 f = ((const float4*)W)[k];
        h4 o = { (_Float16)f.x, (_Float16)f.y, (_Float16)f.z, (_Float16)f.w };
        ((h4*)Wh)[k] = o;
    }
    for (int k = g; k < NX / 4; k += stride) {
        const float4 f = ((const float4*)X)[k];
        h4 o = { (_Float16)f.x, (_Float16)f.y, (_Float16)f.z, (_Float16)f.w };
        ((h4*)Xh)[k] = o;
        // transposed copy XT[(i*256 + b)*8 + q]
        const int e0 = k * 4;
        const int b  = e0 / (II * QQ);
        const int r  = e0 - b * (II * QQ);
        const int i  = r >> 3;
        const int q  = r & 7;
        *(h4*)(XT + ((size_t)i * BB + b) * QQ + q) = o;
    }
    const float4 z = {0.f, 0.f, 0.f, 0.f};
    for (int k = g; k < 3 * NS / 4; k += stride) ((float4*)S)[k] = z;
}

// ---------------------------------------------------------------------------
// s0 via MFMA: s0 = 0.1 * GEMM over K=(i,q)=9216; coalesced A via XT.
// ---------------------------------------------------------------------------
__global__ __launch_bounds__(256) void s0_mfma_kernel(
    const _Float16* __restrict__ XT, const _Float16* __restrict__ Wh,
    float* __restrict__ S0)
{
    const int wid  = blockIdx.x * 4 + (threadIdx.x >> 6);  // 0..1279
    const int lane = threadIdx.x & 63;
    const int bt  = wid / 80;
    const int rem = wid % 80;
    const int j   = rem >> 3;
    const int kc  = rem & 7;
    const int b0  = bt * 16;
    const int m    = lane & 15;
    const int quad = lane >> 4;
    const int ib   = kc * 144;

    const _Float16* ax = XT + ((size_t)(ib + quad) * BB + b0 + m) * QQ;
    const _Float16* bw = Wh + (((size_t)j * II + ib + quad) * PP + m) * QQ;

    f4 acc = {0.f, 0.f, 0.f, 0.f};
    for (int t = 0; t < 36; ++t) {
        const h8 a = *(const h8*)ax;
        const h8 b = *(const h8*)bw;
        acc = __builtin_amdgcn_mfma_f32_16x16x32_f16(a, b, acc, 0, 0, 0);
        ax += (size_t)4 * BB * QQ;
        bw += (size_t)4 * PP * QQ;
    }
#pragma unroll
    for (int r = 0; r < 4; ++r)
        atomicAdd(&S0[((size_t)(b0 + quad * 4 + r) * JJ + j) * PP + m], 0.1f * acc[r]);
}

// ---------------------------------------------------------------------------
// vv_kernel: squash + logit-weight precompute.
//  MODE 0: v = squash(S);  V0raw = v;  VV = v * log2e      (after s0)
//  MODE 1: v = squash(S);  VV = (v + V0raw) * log2e        (after pass 1)
// ---------------------------------------------------------------------------
template <int MODE>
__global__ __launch_bounds__(256) void vv_kernel(
    const float* __restrict__ S, float* __restrict__ V0raw,
    float* __restrict__ VV)
{
    const int idx = blockIdx.x * 256 + threadIdx.x;   // 0..NS-1
    const float s = S[idx];
    const float n2 = row_sum16(s * s);
    const float sc = n2 * __builtin_amdgcn_rcpf(1.0f + n2)
                        * __builtin_amdgcn_rsqf(n2 + 1e-7f);
    const float v = s * sc;
    if (MODE == 0) {
        V0raw[idx] = v;
        VV[idx] = v * LOG2E;
    } else {
        VV[idx] = (v + V0raw[idx]) * LOG2E;
    }
}

// ---------------------------------------------------------------------------
// Fused routing pass — R9 hot loop unchanged (131.6 us best).  R13 change:
// 512-thread block (32 b x 16 p) shares one W tile across 32 b instead of
// 16 -> W re-staging traffic halves (R12 counters: FETCH 51 MB/pass == the
// staging term, ~17 us at measured BW).  Per-thread chain/math/atomics are
// byte-identical to R9.  4 blocks x 512 thr = 2048 thr/CU (32 waves, max).
// ---------------------------------------------------------------------------
__global__ __launch_bounds__(NTH, 6) void pass_kernel(
    const _Float16* __restrict__ Xh,  // [B][I][Q] f16
    const _Float16* __restrict__ Wh,  // [J][I][P][Q] f16
    const float* __restrict__ VV,     // [B][J][P] = v * log2e
    float* __restrict__ Sout)         // [B][J][P] pre-zeroed accumulator
{
    __shared__ _Float16 ws[JJ * WTILE];  // 20 KB
    __shared__ _Float16 xs[BT * XRH];    // 4.5 KB

    // XCD-bijective swizzle (grid 1152 = 8 XCD * 144); bt == XCD id
    const int L  = blockIdx.x;
    const int bt = L & 7;
    const int it = L >> 3;               // 0..143
    const int b0 = bt * BT;
    const int i0 = it * IT;
    const int tid = threadIdx.x;

    // ---- stage W tile: 1280 h8 chunks over 512 threads (16B/lane)
    {
        const size_t jstride = (size_t)II * PP * QQ;
        const _Float16* wsrc = Wh + (size_t)i0 * PP * QQ;
#pragma unroll
        for (int k = 0; k < 3; ++k) {
            const int c = tid + k * NTH;   // 0..1535, guard at 1280
            if (c < 1280) {
                const int j = c >> 7;          // 128 h8 chunks per j
                const int r = c & 127;
                *(h8*)(ws + j * WTILE + r * 8) = *(const h8*)(wsrc + j * jstride + r * 8);
            }
        }
        if (tid < 256) {
            const int xb = tid >> 3;       // 0..31
            const int xr = tid & 7;
            *(h8*)(xs + xb * XRH + xr * 8) =
                *(const h8*)(Xh + ((size_t)(b0 + xb) * II + i0) * QQ + xr * 8);
        }
    }
    __syncthreads();

    const int b_l = tid >> 4;            // 0..31
    const int p   = tid & 15;
    const int b   = b0 + b_l;

    // precomputed vv, packed once into 5 h2 (j-pairs)
    h2 vvpk[5];
#pragma unroll
    for (int jp = 0; jp < JJ; jp += 2) {
        const float v0 = VV[((size_t)b * JJ + jp) * PP + p];
        const float v1 = VV[((size_t)b * JJ + jp + 1) * PP + p];
        vvpk[jp >> 1] = __builtin_bit_cast(h2, __builtin_amdgcn_cvt_pkrtz(v0, v1));
    }

    float sacc[JJ];
#pragma unroll
    for (int j = 0; j < JJ; ++j) sacc[j] = 0.0f;

    const _Float16* wb = ws + p * QQ;    // single LDS base; imm offsets below
    const _Float16* xb = xs + b_l * XRH;

#pragma unroll
    for (int i = 0; i < IT; ++i) {
        const h8 x8 = *(const h8*)(xb + i * QQ);

        float h[JJ];
#pragma unroll
        for (int j = 0; j < JJ; ++j)
            h[j] = dot8(*(const h8*)(wb + j * WTILE + i * PP * QQ), x8);

        // packed-f16 16-lane logit reduction, j-pairs; product via pk_mul
        float e[JJ];
#pragma unroll
        for (int jp = 0; jp < JJ; jp += 2) {
            const h2 hp = __builtin_bit_cast(h2,
                __builtin_amdgcn_cvt_pkrtz(h[jp], h[jp + 1]));
            const h2 r = row_sum16_pk(vvpk[jp >> 1] * hp);
            e[jp]     = __builtin_amdgcn_exp2f((float)r.x);
            e[jp + 1] = __builtin_amdgcn_exp2f((float)r.y);
        }
        float a0 = (e[0] + e[1]) + (e[2] + e[3]);
        float a1 = (e[4] + e[5]) + (e[6] + e[7]);
        const float sum = (a0 + a1) + (e[8] + e[9]);
        const float inv = __builtin_amdgcn_rcpf(sum);
#pragma unroll
        for (int j = 0; j < JJ; ++j) sacc[j] += (e[j] * inv) * h[j];
    }

#pragma unroll
    for (int j = 0; j < JJ; ++j)
        atomicAdd(&Sout[((size_t)b * JJ + j) * PP + p], sacc[j]);
}

// ---------------------------------------------------------------------------
// final output squash (fp32 precise)
// ---------------------------------------------------------------------------
__global__ __launch_bounds__(256) void squash_out_kernel(const float* __restrict__ S,
                                                         float* __restrict__ V)
{
    const int idx = blockIdx.x * blockDim.x + threadIdx.x;  // (b*J + j)
    if (idx >= BB * JJ) return;
    const float4* sp = (const float4*)(S + idx * PP);
    float4 a = sp[0], b4 = sp[1], c4 = sp[2], d4 = sp[3];
    float s2 = a.x * a.x + a.y * a.y + a.z * a.z + a.w * a.w +
               b4.x * b4.x + b4.y * b4.y + b4.z * b4.z + b4.w * b4.w +
               c4.x * c4.x + c4.y * c4.y + c4.z * c4.z + c4.w * c4.w +
               d4.x * d4.x + d4.y * d4.y + d4.z * d4.z + d4.w * d4.w;
    const float scale = s2 / (1.0f + s2) / sqrtf(s2 + 1e-7f);
    a.x *= scale; a.y *= scale; a.z *= scale; a.w *= scale;
    b4.x *= scale; b4.y *= scale; b4.z *= scale; b4.w *= scale;
    c4.x *= scale; c4.y *= scale; c4.z *= scale; c4.w *= scale;
    d4.x *= scale; d4.y *= scale; d4.z *= scale; d4.w *= scale;
    float4* vp = (float4*)(V + idx * PP);
    vp[0] = a; vp[1] = b4; vp[2] = c4; vp[3] = d4;
}

extern "C" void kernel_launch(void* const* d_in, const int* in_sizes, int n_in,
                              void* d_out, int out_size, void* d_ws, size_t ws_size,
                              hipStream_t stream)
{
    const float* X = (const float*)d_in[0];  // [256][1152][8]
    const float* W = (const float*)d_in[1];  // [10][1152][16][8]
    float* out = (float*)d_out;              // [256][10][16]

    _Float16* Xh = (_Float16*)d_ws;          // NX halfs
    _Float16* Wh = Xh + NX;                  // NW halfs
    _Float16* XT = Wh + NW;                  // NX halfs (transposed X for s0)
    float* S0 = (float*)(XT + NX);           // NS floats
    float* S1 = S0 + NS;
    float* S2 = S1 + NS;
    float* V0raw = S2 + NS;                  // NS floats
    float* VV1   = V0raw + NS;               // NS floats
    float* VV2   = VV1 + NS;                 // NS floats; total ~13.3 MB

    const int grid  = NBT * NIT;             // 1152 blocks of 512 threads
    const int vgrid = NS / 256;              // 160 blocks

    prep_kernel<<<1024, 256, 0, stream>>>(X, W, Xh, Wh, XT, S0);
    s0_mfma_kernel<<<320, 256, 0, stream>>>(XT, Wh, S0);
    vv_kernel<0><<<vgrid, 256, 0, stream>>>(S0, V0raw, VV1);
    pass_kernel<<<grid, NTH, 0, stream>>>(Xh, Wh, VV1, S1);
    vv_kernel<1><<<vgrid, 256, 0, stream>>>(S1, V0raw, VV2);
    pass_kernel<<<grid, NTH, 0, stream>>>(Xh, Wh, VV2, S2);
    squash_out_kernel<<<10, 256, 0, stream>>>(S2, out);
}

// Round 14
// 133.842 us; speedup vs baseline: 1.3240x; 1.0531x over previous
//
#include <hip/hip_runtime.h>

typedef _Float16 h2 __attribute__((ext_vector_type(2)));
typedef _Float16 h8 __attribute__((ext_vector_type(8)));
typedef float f4 __attribute__((ext_vector_type(4)));

#define BB 256
#define II 1152
#define QQ 8
#define JJ 10
#define PP 16

#define BT 16            // b per block (R0/R9 proven)
#define IT 8             // i per block
#define NBT (BB / BT)    // 16
#define NIT (II / IT)    // 144
#define XRH 72           // halfs per staged-x b-row (64 + 8 pad)
#define WTILE (IT * PP * QQ)     // 1024 halfs per j in the LDS W-tile

#define NW (JJ * II * PP * QQ)   // 1474560
#define NX (BB * II * QQ)        // 2359296
#define NS (BB * JJ * PP)        // 40960
#define LOG2E 1.4426950408889634f

// ---------------------------------------------------------------------------
// 16-lane row sum via DPP — f32 (for vv_kernel) and packed-f16 (hot loop).
// ---------------------------------------------------------------------------
template <int CTRL>
__device__ __forceinline__ float dpp_add(float v) {
    int s = __builtin_bit_cast(int, v);
    int t = __builtin_amdgcn_update_dpp(0, s, CTRL, 0xF, 0xF, true);
    return v + __builtin_bit_cast(float, t);
}
__device__ __forceinline__ float row_sum16(float v) {
    v = dpp_add<0xB1>(v);   // xor1
    v = dpp_add<0x4E>(v);   // xor2
    v = dpp_add<0x124>(v);  // row_ror:4
    v = dpp_add<0x128>(v);  // row_ror:8
    return v;
}
template <int CTRL>
__device__ __forceinline__ h2 dpp_add_pk(h2 v) {
    int s = __builtin_bit_cast(int, v);
    int t = __builtin_amdgcn_update_dpp(0, s, CTRL, 0xF, 0xF, true);
    return v + __builtin_bit_cast(h2, t);   // v_pk_add_f16
}
__device__ __forceinline__ h2 row_sum16_pk(h2 v) {
    v = dpp_add_pk<0xB1>(v);
    v = dpp_add_pk<0x4E>(v);
    v = dpp_add_pk<0x124>(v);
    v = dpp_add_pk<0x128>(v);
    return v;
}

// 8-element f16 dot with fp32 accumulate: 4 x v_dot2_f32_f16.
__device__ __forceinline__ float dot8(h8 w, h8 x) {
    h2 w0 = __builtin_shufflevector(w, w, 0, 1), w1 = __builtin_shufflevector(w, w, 2, 3);
    h2 w2 = __builtin_shufflevector(w, w, 4, 5), w3 = __builtin_shufflevector(w, w, 6, 7);
    h2 x0 = __builtin_shufflevector(x, x, 0, 1), x1 = __builtin_shufflevector(x, x, 2, 3);
    h2 x2 = __builtin_shufflevector(x, x, 4, 5), x3 = __builtin_shufflevector(x, x, 6, 7);
    float acc = __builtin_amdgcn_fdot2(w0, x0, 0.0f, false);
    acc = __builtin_amdgcn_fdot2(w1, x1, acc, false);
    acc = __builtin_amdgcn_fdot2(w2, x2, acc, false);
    acc = __builtin_amdgcn_fdot2(w3, x3, acc, false);
    return acc;
}

// ---------------------------------------------------------------------------
// prep: W,X fp32 -> f16 (natural Xh + transposed XT[i][b][q] for s0);
// zero S0/S1/S2.
// ---------------------------------------------------------------------------
__global__ __launch_bounds__(256) void prep_kernel(
    const float* __restrict__ X, const float* __restrict__ W,
    _Float16* __restrict__ Xh, _Float16* __restrict__ Wh,
    _Float16* __restrict__ XT,
    float* __restrict__ S)   // 3*NS floats
{
    const int g = blockIdx.x * 256 + threadIdx.x;
    const int stride = gridDim.x * 256;
    typedef _Float16 h4 __attribute__((ext_vector_type(4)));
    for (int k = g; k < NW / 4; k += stride) {
        const float4 f = ((const float4*)W)[k];
        h4 o = { (_Float16)f.x, (_Float16)f.y, (_Float16)f.z, (_Float16)f.w };
        ((h4*)Wh)[k] = o;
    }
    for (int k = g; k < NX / 4; k += stride) {
        const float4 f = ((const float4*)X)[k];
        h4 o = { (_Float16)f.x, (_Float16)f.y, (_Float16)f.z, (_Float16)f.w };
        ((h4*)Xh)[k] = o;
        // transposed copy XT[(i*256 + b)*8 + q]
        const int e0 = k * 4;
        const int b  = e0 / (II * QQ);
        const int r  = e0 - b * (II * QQ);
        const int i  = r >> 3;
        const int q  = r & 7;
        *(h4*)(XT + ((size_t)i * BB + b) * QQ + q) = o;
    }
    const float4 z = {0.f, 0.f, 0.f, 0.f};
    for (int k = g; k < 3 * NS / 4; k += stride) ((float4*)S)[k] = z;
}

// ---------------------------------------------------------------------------
// s0 via MFMA: s0 = 0.1 * GEMM over K=(i,q)=9216; coalesced A via XT.
// ---------------------------------------------------------------------------
__global__ __launch_bounds__(256) void s0_mfma_kernel(
    const _Float16* __restrict__ XT, const _Float16* __restrict__ Wh,
    float* __restrict__ S0)
{
    const int wid  = blockIdx.x * 4 + (threadIdx.x >> 6);  // 0..1279
    const int lane = threadIdx.x & 63;
    const int bt  = wid / 80;
    const int rem = wid % 80;
    const int j   = rem >> 3;
    const int kc  = rem & 7;
    const int b0  = bt * 16;
    const int m    = lane & 15;
    const int quad = lane >> 4;
    const int ib   = kc * 144;

    const _Float16* ax = XT + ((size_t)(ib + quad) * BB + b0 + m) * QQ;
    const _Float16* bw = Wh + (((size_t)j * II + ib + quad) * PP + m) * QQ;

    f4 acc = {0.f, 0.f, 0.f, 0.f};
    for (int t = 0; t < 36; ++t) {
        const h8 a = *(const h8*)ax;
        const h8 b = *(const h8*)bw;
        acc = __builtin_amdgcn_mfma_f32_16x16x32_f16(a, b, acc, 0, 0, 0);
        ax += (size_t)4 * BB * QQ;
        bw += (size_t)4 * PP * QQ;
    }
#pragma unroll
    for (int r = 0; r < 4; ++r)
        atomicAdd(&S0[((size_t)(b0 + quad * 4 + r) * JJ + j) * PP + m], 0.1f * acc[r]);
}

// ---------------------------------------------------------------------------
// vv_kernel: squash + logit-weight precompute.
//  MODE 0: v = squash(S);  V0raw = v;  VV = v * log2e      (after s0)
//  MODE 1: v = squash(S);  VV = (v + V0raw) * log2e        (after pass 1)
// ---------------------------------------------------------------------------
template <int MODE>
__global__ __launch_bounds__(256) void vv_kernel(
    const float* __restrict__ S, float* __restrict__ V0raw,
    float* __restrict__ VV)
{
    const int idx = blockIdx.x * 256 + threadIdx.x;   // 0..NS-1
    const float s = S[idx];
    const float n2 = row_sum16(s * s);
    const float sc = n2 * __builtin_amdgcn_rcpf(1.0f + n2)
                        * __builtin_amdgcn_rsqf(n2 + 1e-7f);
    const float v = s * sc;
    if (MODE == 0) {
        V0raw[idx] = v;
        VV[idx] = v * LOG2E;
    } else {
        VV[idx] = (v + V0raw[idx]) * LOG2E;
    }
}

// ---------------------------------------------------------------------------
// Fused routing pass — EXACT R9 kernel (131.6 us best).  R14: single change,
// __launch_bounds__(256,4) -> (256,7).  R5/R12 counters: occupancy ~30%,
// VALUBusy ~36% -> latency-bound with idle issue slots; the (256,4) bound
// capped residency at 4 blocks/CU while VGPR(64)/LDS(22.25KB) permit 7.
// VGPR cap at 7 waves/EU = 73 >= 64 used (no spill expected; a WRITE_SIZE
// blowup in counters would falsify).
// ---------------------------------------------------------------------------
__global__ __launch_bounds__(256, 7) void pass_kernel(
    const _Float16* __restrict__ Xh,  // [B][I][Q] f16
    const _Float16* __restrict__ Wh,  // [J][I][P][Q] f16
    const float* __restrict__ VV,     // [B][J][P] = v * log2e
    float* __restrict__ Sout)         // [B][J][P] pre-zeroed accumulator
{
    __shared__ _Float16 ws[JJ * WTILE];  // 20 KB
    __shared__ _Float16 xs[BT * XRH];    // 2.25 KB

    // XCD-bijective swizzle (grid 2304 = 8 XCD * 288)
    const int L  = blockIdx.x;
    const int xc = L & 7;
    const int k8 = L >> 3;               // 0..287
    const int bt = 2 * xc + (k8 & 1);
    const int it = k8 >> 1;              // 0..143
    const int b0 = bt * BT;
    const int i0 = it * IT;
    const int tid = threadIdx.x;

    // ---- stage W tile: 1280 h8 chunks, 5 per thread (coalesced 16B/lane)
    {
        const size_t jstride = (size_t)II * PP * QQ;
        const _Float16* wsrc = Wh + (size_t)i0 * PP * QQ;
#pragma unroll
        for (int k = 0; k < 5; ++k) {
            const int c = tid + k * 256;   // 0..1279
            const int j = c >> 7;          // 128 h8 chunks per j
            const int r = c & 127;
            *(h8*)(ws + j * WTILE + r * 8) = *(const h8*)(wsrc + j * jstride + r * 8);
        }
        if (tid < 128) {
            const int xb = tid >> 3;
            const int xr = tid & 7;
            *(h8*)(xs + xb * XRH + xr * 8) =
                *(const h8*)(Xh + ((size_t)(b0 + xb) * II + i0) * QQ + xr * 8);
        }
    }
    __syncthreads();

    const int b_l = tid >> 4;
    const int p   = tid & 15;
    const int b   = b0 + b_l;

    // precomputed vv, packed once into 5 h2 (j-pairs)
    h2 vvpk[5];
#pragma unroll
    for (int jp = 0; jp < JJ; jp += 2) {
        const float v0 = VV[((size_t)b * JJ + jp) * PP + p];
        const float v1 = VV[((size_t)b * JJ + jp + 1) * PP + p];
        vvpk[jp >> 1] = __builtin_bit_cast(h2, __builtin_amdgcn_cvt_pkrtz(v0, v1));
    }

    float sacc[JJ];
#pragma unroll
    for (int j = 0; j < JJ; ++j) sacc[j] = 0.0f;

    const _Float16* wb = ws + p * QQ;    // single LDS base; imm offsets below
    const _Float16* xb = xs + b_l * XRH;

#pragma unroll
    for (int i = 0; i < IT; ++i) {
        const h8 x8 = *(const h8*)(xb + i * QQ);

        float h[JJ];
#pragma unroll
        for (int j = 0; j < JJ; ++j)
            h[j] = dot8(*(const h8*)(wb + j * WTILE + i * PP * QQ), x8);

        // packed-f16 16-lane logit reduction, j-pairs; product via pk_mul
        float e[JJ];
#pragma unroll
        for (int jp = 0; jp < JJ; jp += 2) {
            const h2 hp = __builtin_bit_cast(h2,
                __builtin_amdgcn_cvt_pkrtz(h[jp], h[jp + 1]));
            const h2 r = row_sum16_pk(vvpk[jp >> 1] * hp);
            e[jp]     = __builtin_amdgcn_exp2f((float)r.x);
            e[jp + 1] = __builtin_amdgcn_exp2f((float)r.y);
        }
        float a0 = (e[0] + e[1]) + (e[2] + e[3]);
        float a1 = (e[4] + e[5]) + (e[6] + e[7]);
        const float sum = (a0 + a1) + (e[8] + e[9]);
        const float inv = __builtin_amdgcn_rcpf(sum);
#pragma unroll
        for (int j = 0; j < JJ; ++j) sacc[j] += (e[j] * inv) * h[j];
    }

#pragma unroll
    for (int j = 0; j < JJ; ++j)
        atomicAdd(&Sout[((size_t)b * JJ + j) * PP + p], sacc[j]);
}

// ---------------------------------------------------------------------------
// final output squash (fp32 precise)
// ---------------------------------------------------------------------------
__global__ __launch_bounds__(256) void squash_out_kernel(const float* __restrict__ S,
                                                         float* __restrict__ V)
{
    const int idx = blockIdx.x * blockDim.x + threadIdx.x;  // (b*J + j)
    if (idx >= BB * JJ) return;
    const float4* sp = (const float4*)(S + idx * PP);
    float4 a = sp[0], b4 = sp[1], c4 = sp[2], d4 = sp[3];
    float s2 = a.x * a.x + a.y * a.y + a.z * a.z + a.w * a.w +
               b4.x * b4.x + b4.y * b4.y + b4.z * b4.z + b4.w * b4.w +
               c4.x * c4.x + c4.y * c4.y + c4.z * c4.z + c4.w * c4.w +
               d4.x * d4.x + d4.y * d4.y + d4.z * d4.z + d4.w * d4.w;
    const float scale = s2 / (1.0f + s2) / sqrtf(s2 + 1e-7f);
    a.x *= scale; a.y *= scale; a.z *= scale; a.w *= scale;
    b4.x *= scale; b4.y *= scale; b4.z *= scale; b4.w *= scale;
    c4.x *= scale; c4.y *= scale; c4.z *= scale; c4.w *= scale;
    d4.x *= scale; d4.y *= scale; d4.z *= scale; d4.w *= scale;
    float4* vp = (float4*)(V + idx * PP);
    vp[0] = a; vp[1] = b4; vp[2] = c4; vp[3] = d4;
}

extern "C" void kernel_launch(void* const* d_in, const int* in_sizes, int n_in,
                              void* d_out, int out_size, void* d_ws, size_t ws_size,
                              hipStream_t stream)
{
    const float* X = (const float*)d_in[0];  // [256][1152][8]
    const float* W = (const float*)d_in[1];  // [10][1152][16][8]
    float* out = (float*)d_out;              // [256][10][16]

    _Float16* Xh = (_Float16*)d_ws;          // NX halfs
    _Float16* Wh = Xh + NX;                  // NW halfs
    _Float16* XT = Wh + NW;                  // NX halfs (transposed X for s0)
    float* S0 = (float*)(XT + NX);           // NS floats
    float* S1 = S0 + NS;
    float* S2 = S1 + NS;
    float* V0raw = S2 + NS;                  // NS floats
    float* VV1   = V0raw + NS;               // NS floats
    float* VV2   = VV1 + NS;                 // NS floats; total ~13.3 MB

    const int grid  = NBT * NIT;             // 2304 blocks of 256 threads
    const int vgrid = NS / 256;              // 160 blocks

    prep_kernel<<<1024, 256, 0, stream>>>(X, W, Xh, Wh, XT, S0);
    s0_mfma_kernel<<<320, 256, 0, stream>>>(XT, Wh, S0);
    vv_kernel<0><<<vgrid, 256, 0, stream>>>(S0, V0raw, VV1);
    pass_kernel<<<grid, 256, 0, stream>>>(Xh, Wh, VV1, S1);
    vv_kernel<1><<<vgrid, 256, 0, stream>>>(S1, V0raw, VV2);
    pass_kernel<<<grid, 256, 0, stream>>>(Xh, Wh, VV2, S2);
    squash_out_kernel<<<10, 256, 0, stream>>>(S2, out);
}

// Round 15
// 132.374 us; speedup vs baseline: 1.3387x; 1.0111x over previous
//
#include <hip/hip_runtime.h>

typedef _Float16 h2 __attribute__((ext_vector_type(2)));
typedef _Float16 h8 __attribute__((ext_vector_type(8)));
typedef float f4 __attribute__((ext_vector_type(4)));

#define BB 256
#define II 1152
#define QQ 8
#define JJ 10
#define PP 16

#define BT 16            // b per block (R0/R9 proven)
#define IT 8             // i per block
#define NBT (BB / BT)    // 16
#define NIT (II / IT)    // 144
#define XRH 72           // halfs per staged-x b-row (64 + 8 pad)
#define WTILE (IT * PP * QQ)     // 1024 halfs per j in the LDS W-tile

#define NW (JJ * II * PP * QQ)   // 1474560
#define NX (BB * II * QQ)        // 2359296
#define NS (BB * JJ * PP)        // 40960
#define LOG2E 1.4426950408889634f

// ---------------------------------------------------------------------------
// 16-lane row sum via DPP — f32 (for vv_kernel) and packed-f16 (hot loop).
// ---------------------------------------------------------------------------
template <int CTRL>
__device__ __forceinline__ float dpp_add(float v) {
    int s = __builtin_bit_cast(int, v);
    int t = __builtin_amdgcn_update_dpp(0, s, CTRL, 0xF, 0xF, true);
    return v + __builtin_bit_cast(float, t);
}
__device__ __forceinline__ float row_sum16(float v) {
    v = dpp_add<0xB1>(v);   // xor1
    v = dpp_add<0x4E>(v);   // xor2
    v = dpp_add<0x124>(v);  // row_ror:4
    v = dpp_add<0x128>(v);  // row_ror:8
    return v;
}
template <int CTRL>
__device__ __forceinline__ h2 dpp_add_pk(h2 v) {
    int s = __builtin_bit_cast(int, v);
    int t = __builtin_amdgcn_update_dpp(0, s, CTRL, 0xF, 0xF, true);
    return v + __builtin_bit_cast(h2, t);   // v_pk_add_f16
}
__device__ __forceinline__ h2 row_sum16_pk(h2 v) {
    v = dpp_add_pk<0xB1>(v);
    v = dpp_add_pk<0x4E>(v);
    v = dpp_add_pk<0x124>(v);
    v = dpp_add_pk<0x128>(v);
    return v;
}

// 8-element f16 dot with fp32 accumulate: 4 x v_dot2_f32_f16.
__device__ __forceinline__ float dot8(h8 w, h8 x) {
    h2 w0 = __builtin_shufflevector(w, w, 0, 1), w1 = __builtin_shufflevector(w, w, 2, 3);
    h2 w2 = __builtin_shufflevector(w, w, 4, 5), w3 = __builtin_shufflevector(w, w, 6, 7);
    h2 x0 = __builtin_shufflevector(x, x, 0, 1), x1 = __builtin_shufflevector(x, x, 2, 3);
    h2 x2 = __builtin_shufflevector(x, x, 4, 5), x3 = __builtin_shufflevector(x, x, 6, 7);
    float acc = __builtin_amdgcn_fdot2(w0, x0, 0.0f, false);
    acc = __builtin_amdgcn_fdot2(w1, x1, acc, false);
    acc = __builtin_amdgcn_fdot2(w2, x2, acc, false);
    acc = __builtin_amdgcn_fdot2(w3, x3, acc, false);
    return acc;
}

// ---------------------------------------------------------------------------
// prep: W,X fp32 -> f16 (natural Xh + transposed XT[i][b][q] for s0);
// zero S0/S1/S2.
// ---------------------------------------------------------------------------
__global__ __launch_bounds__(256) void prep_kernel(
    const float* __restrict__ X, const float* __restrict__ W,
    _Float16* __restrict__ Xh, _Float16* __restrict__ Wh,
    _Float16* __restrict__ XT,
    float* __restrict__ S)   // 3*NS floats
{
    const int g = blockIdx.x * 256 + threadIdx.x;
    const int stride = gridDim.x * 256;
    typedef _Float16 h4 __attribute__((ext_vector_type(4)));
    for (int k = g; k < NW / 4; k += stride) {
        const float4 f = ((const float4*)W)[k];
        h4 o = { (_Float16)f.x, (_Float16)f.y, (_Float16)f.z, (_Float16)f.w };
        ((h4*)Wh)[k] = o;
    }
    for (int k = g; k < NX / 4; k += stride) {
        const float4 f = ((const float4*)X)[k];
        h4 o = { (_Float16)f.x, (_Float16)f.y, (_Float16)f.z, (_Float16)f.w };
        ((h4*)Xh)[k] = o;
        // transposed copy XT[(i*256 + b)*8 + q]
        const int e0 = k * 4;
        const int b  = e0 / (II * QQ);
        const int r  = e0 - b * (II * QQ);
        const int i  = r >> 3;
        const int q  = r & 7;
        *(h4*)(XT + ((size_t)i * BB + b) * QQ + q) = o;
    }
    const float4 z = {0.f, 0.f, 0.f, 0.f};
    for (int k = g; k < 3 * NS / 4; k += stride) ((float4*)S)[k] = z;
}

// ---------------------------------------------------------------------------
// s0 via MFMA: s0 = 0.1 * GEMM over K=(i,q)=9216; coalesced A via XT.
// ---------------------------------------------------------------------------
__global__ __launch_bounds__(256) void s0_mfma_kernel(
    const _Float16* __restrict__ XT, const _Float16* __restrict__ Wh,
    float* __restrict__ S0)
{
    const int wid  = blockIdx.x * 4 + (threadIdx.x >> 6);  // 0..1279
    const int lane = threadIdx.x & 63;
    const int bt  = wid / 80;
    const int rem = wid % 80;
    const int j   = rem >> 3;
    const int kc  = rem & 7;
    const int b0  = bt * 16;
    const int m    = lane & 15;
    const int quad = lane >> 4;
    const int ib   = kc * 144;

    const _Float16* ax = XT + ((size_t)(ib + quad) * BB + b0 + m) * QQ;
    const _Float16* bw = Wh + (((size_t)j * II + ib + quad) * PP + m) * QQ;

    f4 acc = {0.f, 0.f, 0.f, 0.f};
    for (int t = 0; t < 36; ++t) {
        const h8 a = *(const h8*)ax;
        const h8 b = *(const h8*)bw;
        acc = __builtin_amdgcn_mfma_f32_16x16x32_f16(a, b, acc, 0, 0, 0);
        ax += (size_t)4 * BB * QQ;
        bw += (size_t)4 * PP * QQ;
    }
#pragma unroll
    for (int r = 0; r < 4; ++r)
        atomicAdd(&S0[((size_t)(b0 + quad * 4 + r) * JJ + j) * PP + m], 0.1f * acc[r]);
}

// ---------------------------------------------------------------------------
// vv_kernel: squash + logit-weight precompute.
//  MODE 0: v = squash(S);  V0raw = v;  VV = v * log2e      (after s0)
//  MODE 1: v = squash(S);  VV = (v + V0raw) * log2e        (after pass 1)
// ---------------------------------------------------------------------------
template <int MODE>
__global__ __launch_bounds__(256) void vv_kernel(
    const float* __restrict__ S, float* __restrict__ V0raw,
    float* __restrict__ VV)
{
    const int idx = blockIdx.x * 256 + threadIdx.x;   // 0..NS-1
    const float s = S[idx];
    const float n2 = row_sum16(s * s);
    const float sc = n2 * __builtin_amdgcn_rcpf(1.0f + n2)
                        * __builtin_amdgcn_rsqf(n2 + 1e-7f);
    const float v = s * sc;
    if (MODE == 0) {
        V0raw[idx] = v;
        VV[idx] = v * LOG2E;
    } else {
        VV[idx] = (v + V0raw[idx]) * LOG2E;
    }
}

// ---------------------------------------------------------------------------
// Fused routing pass — R9 geometry/staging/atomics (131.6 us best), R15:
// hot loop processes i in PAIRS with fully interleaved chains.  Ledger
// (R1/R10/R11/R13/R14) exonerated VALU-issue, DS-BW, staging, occupancy ->
// theory: intra-wave ILP starvation in the serial dot8->DPP->exp2 chain.
// Pairing doubles independent chains (10 DPP chains live vs 5).
// Est. ~80 live VGPR < 128 cap from (256,4) — no spill (R12's failure was
// 140 VGPR; falsifier = WRITE_SIZE blowup on pass dispatches).
// ---------------------------------------------------------------------------
__global__ __launch_bounds__(256, 4) void pass_kernel(
    const _Float16* __restrict__ Xh,  // [B][I][Q] f16
    const _Float16* __restrict__ Wh,  // [J][I][P][Q] f16
    const float* __restrict__ VV,     // [B][J][P] = v * log2e
    float* __restrict__ Sout)         // [B][J][P] pre-zeroed accumulator
{
    __shared__ _Float16 ws[JJ * WTILE];  // 20 KB
    __shared__ _Float16 xs[BT * XRH];    // 2.25 KB

    // XCD-bijective swizzle (grid 2304 = 8 XCD * 288)
    const int L  = blockIdx.x;
    const int xc = L & 7;
    const int k8 = L >> 3;               // 0..287
    const int bt = 2 * xc + (k8 & 1);
    const int it = k8 >> 1;              // 0..143
    const int b0 = bt * BT;
    const int i0 = it * IT;
    const int tid = threadIdx.x;

    // ---- stage W tile: 1280 h8 chunks, 5 per thread (coalesced 16B/lane)
    {
        const size_t jstride = (size_t)II * PP * QQ;
        const _Float16* wsrc = Wh + (size_t)i0 * PP * QQ;
#pragma unroll
        for (int k = 0; k < 5; ++k) {
            const int c = tid + k * 256;   // 0..1279
            const int j = c >> 7;          // 128 h8 chunks per j
            const int r = c & 127;
            *(h8*)(ws + j * WTILE + r * 8) = *(const h8*)(wsrc + j * jstride + r * 8);
        }
        if (tid < 128) {
            const int xb = tid >> 3;
            const int xr = tid & 7;
            *(h8*)(xs + xb * XRH + xr * 8) =
                *(const h8*)(Xh + ((size_t)(b0 + xb) * II + i0) * QQ + xr * 8);
        }
    }
    __syncthreads();

    const int b_l = tid >> 4;
    const int p   = tid & 15;
    const int b   = b0 + b_l;

    // precomputed vv, packed once into 5 h2 (j-pairs)
    h2 vvpk[5];
#pragma unroll
    for (int jp = 0; jp < JJ; jp += 2) {
        const float v0 = VV[((size_t)b * JJ + jp) * PP + p];
        const float v1 = VV[((size_t)b * JJ + jp + 1) * PP + p];
        vvpk[jp >> 1] = __builtin_bit_cast(h2, __builtin_amdgcn_cvt_pkrtz(v0, v1));
    }

    float sacc[JJ];
#pragma unroll
    for (int j = 0; j < JJ; ++j) sacc[j] = 0.0f;

    const _Float16* wb = ws + p * QQ;    // single LDS base; imm offsets below
    const _Float16* xb = xs + b_l * XRH;

#pragma unroll
    for (int i2 = 0; i2 < IT; i2 += 2) {
        const h8 xA = *(const h8*)(xb + i2 * QQ);
        const h8 xB = *(const h8*)(xb + (i2 + 1) * QQ);

        float hA[JJ], hB[JJ];
#pragma unroll
        for (int j = 0; j < JJ; ++j) {
            hA[j] = dot8(*(const h8*)(wb + j * WTILE + i2 * PP * QQ), xA);
            hB[j] = dot8(*(const h8*)(wb + j * WTILE + (i2 + 1) * PP * QQ), xB);
        }

        // interleaved packed-f16 16-lane logit reductions: 10 independent
        // DPP chains in flight (5 packs x 2 i)
        float eA[JJ], eB[JJ];
#pragma unroll
        for (int jp = 0; jp < JJ; jp += 2) {
            const h2 hpA = __builtin_bit_cast(h2,
                __builtin_amdgcn_cvt_pkrtz(hA[jp], hA[jp + 1]));
            const h2 hpB = __builtin_bit_cast(h2,
                __builtin_amdgcn_cvt_pkrtz(hB[jp], hB[jp + 1]));
            const h2 rA = row_sum16_pk(vvpk[jp >> 1] * hpA);
            const h2 rB = row_sum16_pk(vvpk[jp >> 1] * hpB);
            eA[jp]     = __builtin_amdgcn_exp2f((float)rA.x);
            eA[jp + 1] = __builtin_amdgcn_exp2f((float)rA.y);
            eB[jp]     = __builtin_amdgcn_exp2f((float)rB.x);
            eB[jp + 1] = __builtin_amdgcn_exp2f((float)rB.y);
        }
        float a0A = (eA[0] + eA[1]) + (eA[2] + eA[3]);
        float a1A = (eA[4] + eA[5]) + (eA[6] + eA[7]);
        const float sumA = (a0A + a1A) + (eA[8] + eA[9]);
        float a0B = (eB[0] + eB[1]) + (eB[2] + eB[3]);
        float a1B = (eB[4] + eB[5]) + (eB[6] + eB[7]);
        const float sumB = (a0B + a1B) + (eB[8] + eB[9]);
        const float invA = __builtin_amdgcn_rcpf(sumA);
        const float invB = __builtin_amdgcn_rcpf(sumB);
#pragma unroll
        for (int j = 0; j < JJ; ++j) {
            sacc[j] += (eA[j] * invA) * hA[j];
            sacc[j] += (eB[j] * invB) * hB[j];
        }
    }

#pragma unroll
    for (int j = 0; j < JJ; ++j)
        atomicAdd(&Sout[((size_t)b * JJ + j) * PP + p], sacc[j]);
}

// ---------------------------------------------------------------------------
// final output squash (fp32 precise)
// ---------------------------------------------------------------------------
__global__ __launch_bounds__(256) void squash_out_kernel(const float* __restrict__ S,
                                                         float* __restrict__ V)
{
    const int idx = blockIdx.x * blockDim.x + threadIdx.x;  // (b*J + j)
    if (idx >= BB * JJ) return;
    const float4* sp = (const float4*)(S + idx * PP);
    float4 a = sp[0], b4 = sp[1], c4 = sp[2], d4 = sp[3];
    float s2 = a.x * a.x + a.y * a.y + a.z * a.z + a.w * a.w +
               b4.x * b4.x + b4.y * b4.y + b4.z * b4.z + b4.w * b4.w +
               c4.x * c4.x + c4.y * c4.y + c4.z * c4.z + c4.w * c4.w +
               d4.x * d4.x + d4.y * d4.y + d4.z * d4.z + d4.w * d4.w;
    const float scale = s2 / (1.0f + s2) / sqrtf(s2 + 1e-7f);
    a.x *= scale; a.y *= scale; a.z *= scale; a.w *= scale;
    b4.x *= scale; b4.y *= scale; b4.z *= scale; b4.w *= scale;
    c4.x *= scale; c4.y *= scale; c4.z *= scale; c4.w *= scale;
    d4.x *= scale; d4.y *= scale; d4.z *= scale; d4.w *= scale;
    float4* vp = (float4*)(V + idx * PP);
    vp[0] = a; vp[1] = b4; vp[2] = c4; vp[3] = d4;
}

extern "C" void kernel_launch(void* const* d_in, const int* in_sizes, int n_in,
                              void* d_out, int out_size, void* d_ws, size_t ws_size,
                              hipStream_t stream)
{
    const float* X = (const float*)d_in[0];  // [256][1152][8]
    const float* W = (const float*)d_in[1];  // [10][1152][16][8]
    float* out = (float*)d_out;              // [256][10][16]

    _Float16* Xh = (_Float16*)d_ws;          // NX halfs
    _Float16* Wh = Xh + NX;                  // NW halfs
    _Float16* XT = Wh + NW;                  // NX halfs (transposed X for s0)
    float* S0 = (float*)(XT + NX);           // NS floats
    float* S1 = S0 + NS;
    float* S2 = S1 + NS;
    float* V0raw = S2 + NS;                  // NS floats
    float* VV1   = V0raw + NS;               // NS floats
    float* VV2   = VV1 + NS;                 // NS floats; total ~13.3 MB

    const int grid  = NBT * NIT;             // 2304 blocks of 256 threads
    const int vgrid = NS / 256;              // 160 blocks

    prep_kernel<<<1024, 256, 0, stream>>>(X, W, Xh, Wh, XT, S0);
    s0_mfma_kernel<<<320, 256, 0, stream>>>(XT, Wh, S0);
    vv_kernel<0><<<vgrid, 256, 0, stream>>>(S0, V0raw, VV1);
    pass_kernel<<<grid, 256, 0, stream>>>(Xh, Wh, VV1, S1);
    vv_kernel<1><<<vgrid, 256, 0, stream>>>(S1, V0raw, VV2);
    pass_kernel<<<grid, 256, 0, stream>>>(Xh, Wh, VV2, S2);
    squash_out_kernel<<<10, 256, 0, stream>>>(S2, out);
}